// Round 2
// baseline (180928.394 us; speedup 1.0000x reference)
//
#include <hip/hip_runtime.h>

// Persistent-LSTM kernel for MI355X — Round 2.
// Round-1 failure: float4 w[8][8] was NOT SROA-promoted (VGPR_Count=180) and
// lived in scratch -> 1.3 TB of HBM spill traffic per call at 6.3 TB/s = 180 ms.
// Fix: 64 individually-NAMED float4 weight registers + macro-expanded
// literal-index load/FMA code so SROA cannot bail. Everything else unchanged.
//
// 256 blocks x 256 threads, 1 block/CU (__launch_bounds__(256,1) -> 512-VGPR
// budget, 1 wave/SIMD). Block b owns h-indices [8b,8b+8); wave wv owns
// j0=8b+2wv, j0+1 with all 4 gates. Lane ln owns float4 chunks {ln+64k}.
// Cross-XCD h broadcast via agent-scope atomics (resolve at Infinity Cache);
// leaf-counter barrier (8 leaves, 128 arrivals/step).

#define H      2048
#define TSTEPS 8192
#define FEAT   128
#define NBLK   256
#define NTHR   256
#define RESET_TH 0x10000000u

__device__ __forceinline__ float sigm(float xv) {
  return __builtin_amdgcn_rcpf(1.0f + __expf(-xv));
}
__device__ __forceinline__ float tanh_(float xv) {
  return 1.0f - 2.0f * __builtin_amdgcn_rcpf(__expf(2.0f * xv) + 1.0f);
}

union F2U { unsigned long long u; float2 f; };

// ---------- macro-expanded register file ----------
#define DECLROW(r) float4 w##r##_0, w##r##_1, w##r##_2, w##r##_3, \
                          w##r##_4, w##r##_5, w##r##_6, w##r##_7; \
                   float2 wih##r; float bias##r; float acc##r;

#define LOADROW(r, rowidx) { \
  const float* wr_ = W_hh + (long)(rowidx) * H; \
  w##r##_0 = *(const float4*)(wr_ + 4*(ln      )); \
  w##r##_1 = *(const float4*)(wr_ + 4*(ln +  64)); \
  w##r##_2 = *(const float4*)(wr_ + 4*(ln + 128)); \
  w##r##_3 = *(const float4*)(wr_ + 4*(ln + 192)); \
  w##r##_4 = *(const float4*)(wr_ + 4*(ln + 256)); \
  w##r##_5 = *(const float4*)(wr_ + 4*(ln + 320)); \
  w##r##_6 = *(const float4*)(wr_ + 4*(ln + 384)); \
  w##r##_7 = *(const float4*)(wr_ + 4*(ln + 448)); \
  wih##r  = *(const float2*)(W_ih + (long)(rowidx) * FEAT + 2*ln); \
  bias##r = b_ih[rowidx] + b_hh[rowidx]; }

#define STAGE_CHUNK(k, src, ldsrow) { \
  F2U lo_, hi_; \
  const float* p_ = (src) + 4*(ln + 64*(k)); \
  lo_.u = __hip_atomic_load((const unsigned long long*)p_, \
                            __ATOMIC_RELAXED, __HIP_MEMORY_SCOPE_AGENT); \
  hi_.u = __hip_atomic_load((const unsigned long long*)(p_ + 2), \
                            __ATOMIC_RELAXED, __HIP_MEMORY_SCOPE_AGENT); \
  hv##k = make_float4(lo_.f.x, lo_.f.y, hi_.f.x, hi_.f.y); \
  *(float4*)&(ldsrow)[4*(ln + 64*(k))] = hv##k; }

#define LDSREAD_CHUNK(k, ldsrow) \
  hv##k = *(const float4*)&(ldsrow)[4*(ln + 64*(k))];

#define FMA_RC(r, c) \
  acc##r = __builtin_fmaf(w##r##_##c.x, h4_.x, acc##r); \
  acc##r = __builtin_fmaf(w##r##_##c.y, h4_.y, acc##r); \
  acc##r = __builtin_fmaf(w##r##_##c.z, h4_.z, acc##r); \
  acc##r = __builtin_fmaf(w##r##_##c.w, h4_.w, acc##r);

#define FMA_CHUNK(c) { const float4 h4_ = hv##c; \
  FMA_RC(0, c) FMA_RC(1, c) FMA_RC(2, c) FMA_RC(3, c) \
  FMA_RC(4, c) FMA_RC(5, c) FMA_RC(6, c) FMA_RC(7, c) }

#define REDUCE(r) { float a_ = acc##r; \
  a_ += __shfl_xor(a_, 1);  a_ += __shfl_xor(a_, 2);  a_ += __shfl_xor(a_, 4); \
  a_ += __shfl_xor(a_, 8);  a_ += __shfl_xor(a_, 16); a_ += __shfl_xor(a_, 32); \
  acc##r = a_ + bias##r; }

#define LINFMA(k) { const float4 h4_ = hv##k; \
  const float4 u0_ = *(const float4*)(wl0 + 4*(ln + 64*(k))); \
  const float4 u1_ = *(const float4*)(wl1 + 4*(ln + 64*(k))); \
  a0 += u0_.x*h4_.x + u0_.y*h4_.y + u0_.z*h4_.z + u0_.w*h4_.w; \
  a1 += u1_.x*h4_.x + u1_.y*h4_.y + u1_.z*h4_.z + u1_.w*h4_.w; }

__global__ __launch_bounds__(NTHR, 1)
void lstm_persist(const float* __restrict__ x,
                  const float* __restrict__ W_ih,
                  const float* __restrict__ W_hh,
                  const float* __restrict__ b_ih,
                  const float* __restrict__ b_hh,
                  const float* __restrict__ W_lin,
                  const float* __restrict__ b_lin,
                  const float* __restrict__ W_out,
                  const float* __restrict__ b_out,
                  float* __restrict__ out,
                  float* __restrict__ ws)
{
  const int tid = threadIdx.x;
  const int b   = blockIdx.x;
  const int wv  = tid >> 6;
  const int ln  = tid & 63;

  float* hbuf0 = ws;            // [2048] ping
  float* hbuf1 = ws + H;        // [2048] pong
  float* ylin  = ws + 2 * H;    // [2048] first-linear output
  unsigned* leaves = (unsigned*)(ws + 4 * H);   // 8 counters, 64 uints apart
  unsigned* myleaf = leaves + (b & 7) * 64;

  __shared__ __align__(16) float h_lds[2][H];

  // ---- barrier-leaf reset (ws re-poisoned to 0xAA every launch) ----
  if (tid == 0 && b < 8) {
    if (__hip_atomic_load(leaves + b * 64, __ATOMIC_RELAXED,
                          __HIP_MEMORY_SCOPE_AGENT) >= RESET_TH)
      __hip_atomic_store(leaves + b * 64, 0u, __ATOMIC_RELAXED,
                         __HIP_MEMORY_SCOPE_AGENT);
  }
  if (ln == 0) {
    while (__hip_atomic_load(myleaf, __ATOMIC_RELAXED,
                             __HIP_MEMORY_SCOPE_AGENT) >= RESET_TH) {}
  }

  // ---- load persistent weights into NAMED registers ----
  const int j0 = b * 8 + wv * 2;
  DECLROW(0) DECLROW(1) DECLROW(2) DECLROW(3)
  DECLROW(4) DECLROW(5) DECLROW(6) DECLROW(7)
  float4 hv0, hv1, hv2, hv3, hv4, hv5, hv6, hv7;

  LOADROW(0, 0 * H + j0)     LOADROW(1, 0 * H + j0 + 1)
  LOADROW(2, 1 * H + j0)     LOADROW(3, 1 * H + j0 + 1)
  LOADROW(4, 2 * H + j0)     LOADROW(5, 2 * H + j0 + 1)
  LOADROW(6, 3 * H + j0)     LOADROW(7, 3 * H + j0 + 1)

  // ---- init h0 = 0 and arrive (arrival #1 per wave) ----
  if (ln == 0) {
    F2U z; z.f = make_float2(0.0f, 0.0f);
    __hip_atomic_store((unsigned long long*)(hbuf0 + j0), z.u,
                       __ATOMIC_RELAXED, __HIP_MEMORY_SCOPE_AGENT);
    __hip_atomic_fetch_add(myleaf, 1u, __ATOMIC_RELEASE,
                           __HIP_MEMORY_SCOPE_AGENT);
  }

  float c0 = 0.0f, c1 = 0.0f;
  float2 xr = *(const float2*)(x + 2 * ln);   // prefetch x row 0

  #pragma unroll 1
  for (int t = 0; t < TSTEPS; ++t) {
    const float* hsrc = (t & 1) ? hbuf1 : hbuf0;
    float* ldsrow = h_lds[t & 1];

    if (wv == 0) {
      // wait for all 1024 waves to have produced h_t
      const unsigned target = 128u * (unsigned)(t + 1);
      const unsigned* lp = leaves + (ln & 7) * 64;
      while (true) {
        unsigned v = __hip_atomic_load(lp, __ATOMIC_RELAXED,
                                       __HIP_MEMORY_SCOPE_AGENT);
        if (__all(v >= target)) break;
      }
      __builtin_amdgcn_fence(__ATOMIC_ACQUIRE, "agent");
      STAGE_CHUNK(0, hsrc, ldsrow) STAGE_CHUNK(1, hsrc, ldsrow)
      STAGE_CHUNK(2, hsrc, ldsrow) STAGE_CHUNK(3, hsrc, ldsrow)
      STAGE_CHUNK(4, hsrc, ldsrow) STAGE_CHUNK(5, hsrc, ldsrow)
      STAGE_CHUNK(6, hsrc, ldsrow) STAGE_CHUNK(7, hsrc, ldsrow)
    }
    __syncthreads();
    if (wv != 0) {
      LDSREAD_CHUNK(0, ldsrow) LDSREAD_CHUNK(1, ldsrow)
      LDSREAD_CHUNK(2, ldsrow) LDSREAD_CHUNK(3, ldsrow)
      LDSREAD_CHUNK(4, ldsrow) LDSREAD_CHUNK(5, ldsrow)
      LDSREAD_CHUNK(6, ldsrow) LDSREAD_CHUNK(7, ldsrow)
    }

    // x-projection partial (2 cols) + recurrent matvec partial (32 cols)
    acc0 = wih0.x * xr.x + wih0.y * xr.y;
    acc1 = wih1.x * xr.x + wih1.y * xr.y;
    acc2 = wih2.x * xr.x + wih2.y * xr.y;
    acc3 = wih3.x * xr.x + wih3.y * xr.y;
    acc4 = wih4.x * xr.x + wih4.y * xr.y;
    acc5 = wih5.x * xr.x + wih5.y * xr.y;
    acc6 = wih6.x * xr.x + wih6.y * xr.y;
    acc7 = wih7.x * xr.x + wih7.y * xr.y;

    FMA_CHUNK(0) FMA_CHUNK(1) FMA_CHUNK(2) FMA_CHUNK(3)
    FMA_CHUNK(4) FMA_CHUNK(5) FMA_CHUNK(6) FMA_CHUNK(7)

    // prefetch next x row (address known in advance, unlike h)
    {
      const int tn = (t + 1 < TSTEPS) ? (t + 1) : 0;
      xr = *(const float2*)(x + (long)tn * FEAT + 2 * ln);
    }

    // reduce each gate pre-activation across 64 lanes
    REDUCE(0) REDUCE(1) REDUCE(2) REDUCE(3)
    REDUCE(4) REDUCE(5) REDUCE(6) REDUCE(7)

    // LSTM cell for this wave's 2 hidden units (all lanes redundant)
    const float i0 = sigm(acc0),  i1 = sigm(acc1);
    const float f0 = sigm(acc2),  f1 = sigm(acc3);
    const float g0 = tanh_(acc4), g1 = tanh_(acc5);
    const float o0 = sigm(acc6),  o1 = sigm(acc7);
    c0 = f0 * c0 + i0 * g0;
    c1 = f1 * c1 + i1 * g1;
    const float h0 = o0 * tanh_(c0);
    const float h1 = o1 * tanh_(c1);

    if (ln == 0) {
      float* hdst = ((t + 1) & 1) ? hbuf1 : hbuf0;
      F2U hv2_; hv2_.f = make_float2(h0, h1);
      __hip_atomic_store((unsigned long long*)(hdst + j0), hv2_.u,
                         __ATOMIC_RELAXED, __HIP_MEMORY_SCOPE_AGENT);
      __hip_atomic_fetch_add(myleaf, 1u, __ATOMIC_RELEASE,
                             __HIP_MEMORY_SCOPE_AGENT);
    }
  }

  // ---- head phase 1: ylin[j] = b_lin[j] + sum_k W_lin[j,k]*h_final[k] ----
  {
    const float* hsrc = hbuf0;   // h_8192 lives in parity-0 buffer
    float* ldsrow = h_lds[0];
    if (wv == 0) {
      const unsigned target = 128u * (unsigned)(TSTEPS + 1);
      const unsigned* lp = leaves + (ln & 7) * 64;
      while (true) {
        unsigned v = __hip_atomic_load(lp, __ATOMIC_RELAXED,
                                       __HIP_MEMORY_SCOPE_AGENT);
        if (__all(v >= target)) break;
      }
      __builtin_amdgcn_fence(__ATOMIC_ACQUIRE, "agent");
      STAGE_CHUNK(0, hsrc, ldsrow) STAGE_CHUNK(1, hsrc, ldsrow)
      STAGE_CHUNK(2, hsrc, ldsrow) STAGE_CHUNK(3, hsrc, ldsrow)
      STAGE_CHUNK(4, hsrc, ldsrow) STAGE_CHUNK(5, hsrc, ldsrow)
      STAGE_CHUNK(6, hsrc, ldsrow) STAGE_CHUNK(7, hsrc, ldsrow)
    }
    __syncthreads();
    if (wv != 0) {
      LDSREAD_CHUNK(0, ldsrow) LDSREAD_CHUNK(1, ldsrow)
      LDSREAD_CHUNK(2, ldsrow) LDSREAD_CHUNK(3, ldsrow)
      LDSREAD_CHUNK(4, ldsrow) LDSREAD_CHUNK(5, ldsrow)
      LDSREAD_CHUNK(6, ldsrow) LDSREAD_CHUNK(7, ldsrow)
    }

    float a0 = 0.0f, a1 = 0.0f;
    const float* wl0 = W_lin + (long)j0 * H;
    const float* wl1 = W_lin + (long)(j0 + 1) * H;
    LINFMA(0) LINFMA(1) LINFMA(2) LINFMA(3)
    LINFMA(4) LINFMA(5) LINFMA(6) LINFMA(7)

    a0 += __shfl_xor(a0, 1);  a0 += __shfl_xor(a0, 2);  a0 += __shfl_xor(a0, 4);
    a0 += __shfl_xor(a0, 8);  a0 += __shfl_xor(a0, 16); a0 += __shfl_xor(a0, 32);
    a1 += __shfl_xor(a1, 1);  a1 += __shfl_xor(a1, 2);  a1 += __shfl_xor(a1, 4);
    a1 += __shfl_xor(a1, 8);  a1 += __shfl_xor(a1, 16); a1 += __shfl_xor(a1, 32);

    if (ln == 0) {
      F2U yv_; yv_.f = make_float2(a0 + b_lin[j0], a1 + b_lin[j0 + 1]);
      __hip_atomic_store((unsigned long long*)(ylin + j0), yv_.u,
                         __ATOMIC_RELAXED, __HIP_MEMORY_SCOPE_AGENT);
      __hip_atomic_fetch_add(myleaf, 1u, __ATOMIC_RELEASE,
                             __HIP_MEMORY_SCOPE_AGENT);
    }
  }

  // ---- head phase 2: y = ylin @ W_out.T + b_out (block 0, wave 0 only) ----
  if (b == 0 && wv == 0) {
    const unsigned target = 128u * (unsigned)(TSTEPS + 2);
    const unsigned* lp = leaves + (ln & 7) * 64;
    while (true) {
      unsigned v = __hip_atomic_load(lp, __ATOMIC_RELAXED,
                                     __HIP_MEMORY_SCOPE_AGENT);
      if (__all(v >= target)) break;
    }
    __builtin_amdgcn_fence(__ATOMIC_ACQUIRE, "agent");
    float p0 = 0.0f, p1 = 0.0f;
    #pragma unroll
    for (int k = 0; k < 8; ++k) {
      const int c = 4 * (ln + 64 * k);
      F2U ylo, yhi;
      ylo.u = __hip_atomic_load((const unsigned long long*)(ylin + c),
                                __ATOMIC_RELAXED, __HIP_MEMORY_SCOPE_AGENT);
      yhi.u = __hip_atomic_load((const unsigned long long*)(ylin + c + 2),
                                __ATOMIC_RELAXED, __HIP_MEMORY_SCOPE_AGENT);
      const float4 yv = make_float4(ylo.f.x, ylo.f.y, yhi.f.x, yhi.f.y);
      const float4 q0 = *(const float4*)(W_out + c);
      const float4 q1 = *(const float4*)(W_out + H + c);
      p0 += q0.x * yv.x + q0.y * yv.y + q0.z * yv.z + q0.w * yv.w;
      p1 += q1.x * yv.x + q1.y * yv.y + q1.z * yv.z + q1.w * yv.w;
    }
    p0 += __shfl_xor(p0, 1);  p0 += __shfl_xor(p0, 2);  p0 += __shfl_xor(p0, 4);
    p0 += __shfl_xor(p0, 8);  p0 += __shfl_xor(p0, 16); p0 += __shfl_xor(p0, 32);
    p1 += __shfl_xor(p1, 1);  p1 += __shfl_xor(p1, 2);  p1 += __shfl_xor(p1, 4);
    p1 += __shfl_xor(p1, 8);  p1 += __shfl_xor(p1, 16); p1 += __shfl_xor(p1, 32);
    if (ln == 0) {
      out[0] = p0 + b_out[0];
      out[1] = p1 + b_out[1];
    }
  }
}

extern "C" void kernel_launch(void* const* d_in, const int* in_sizes, int n_in,
                              void* d_out, int out_size, void* d_ws, size_t ws_size,
                              hipStream_t stream) {
  const float* x     = (const float*)d_in[0];
  const float* W_ih  = (const float*)d_in[1];
  const float* W_hh  = (const float*)d_in[2];
  const float* b_ih  = (const float*)d_in[3];
  const float* b_hh  = (const float*)d_in[4];
  const float* W_lin = (const float*)d_in[5];
  const float* b_lin = (const float*)d_in[6];
  const float* W_out = (const float*)d_in[7];
  const float* b_out = (const float*)d_in[8];

  lstm_persist<<<dim3(NBLK), dim3(NTHR), 0, stream>>>(
      x, W_ih, W_hh, b_ih, b_hh, W_lin, b_lin, W_out, b_out,
      (float*)d_out, (float*)d_ws);
}

// Round 3
// 37450.491 us; speedup vs baseline: 4.8311x; 4.8311x over previous
//
#include <hip/hip_runtime.h>

// Persistent-LSTM MI355X — Round 3.
// R2 diagnosis: (a) allocator SANK the invariant W_hh loads into the loop
// (VGPR=176, weights never register-resident); (b) per-step agent-scope
// acquire fence = buffer_inv -> full L2 invalidate every step -> 64 MiB/step
// re-pulled from L3 = 180 ms. HBM counters tiny (1.3 GB) -> L3-bound, not HBM.
// Fixes: asm-pinned weight registers (non-rematerializable), 512-thr blocks
// (1 hidden unit/wave -> only 128 weight VGPRs/lane, live set ~190 < 256),
// and NO agent fences in the loop (per-access agent atomics + syncthreads
// vmcnt-drain + workgroup fences only -> no buffer_inv / buffer_wbl2).
//
// 256 blocks x 512 threads. VGPR in (128,256] -> exactly 1 block/CU -> all
// 256 blocks co-resident -> spin barrier safe. Block b owns h[8b..8b+8);
// wave wv owns unit j = 8b+wv (4 gate rows j, H+j, 2H+j, 3H+j). Lane ln owns
// float4 chunks {ln+64k, k=0..7} of each row.
// Barrier: 8 leaf counters (64B apart), leader-only arrive (256 RMW/step),
// 32 increments per leaf per step; wave0 lanes 0..7 poll.

#define H      2048
#define TSTEPS 8192
#define FEAT   128
#define NBLK   256
#define NTHR   512
#define RESET_TH 0x10000000u

typedef float vf4 __attribute__((ext_vector_type(4)));
typedef float vf2 __attribute__((ext_vector_type(2)));

__device__ __forceinline__ float sigm(float xv) {
  return __builtin_amdgcn_rcpf(1.0f + __expf(-xv));
}
__device__ __forceinline__ float tanh_(float xv) {
  return 1.0f - 2.0f * __builtin_amdgcn_rcpf(__expf(2.0f * xv) + 1.0f);
}

union F2U { unsigned long long u; float2 f; };

#define DECLG(g) vf4 w##g##_0, w##g##_1, w##g##_2, w##g##_3, \
                     w##g##_4, w##g##_5, w##g##_6, w##g##_7; \
                 vf2 wih##g; float bias##g; float acc##g;

#define LOADG(g) { \
  const int row_ = (g) * H + j; \
  const float* wr_ = W_hh + (long)row_ * H; \
  w##g##_0 = *(const vf4*)(wr_ + 4*(ln      )); \
  w##g##_1 = *(const vf4*)(wr_ + 4*(ln +  64)); \
  w##g##_2 = *(const vf4*)(wr_ + 4*(ln + 128)); \
  w##g##_3 = *(const vf4*)(wr_ + 4*(ln + 192)); \
  w##g##_4 = *(const vf4*)(wr_ + 4*(ln + 256)); \
  w##g##_5 = *(const vf4*)(wr_ + 4*(ln + 320)); \
  w##g##_6 = *(const vf4*)(wr_ + 4*(ln + 384)); \
  w##g##_7 = *(const vf4*)(wr_ + 4*(ln + 448)); \
  wih##g  = *(const vf2*)(W_ih + (long)row_ * FEAT + 2*ln); \
  bias##g = b_ih[row_] + b_hh[row_]; }

// Opaque register pin: values become non-rematerializable -> the allocator
// cannot re-sink the W_hh loads into the loop.
#define PIN(g) asm volatile("" : \
  "+v"(w##g##_0), "+v"(w##g##_1), "+v"(w##g##_2), "+v"(w##g##_3), \
  "+v"(w##g##_4), "+v"(w##g##_5), "+v"(w##g##_6), "+v"(w##g##_7), \
  "+v"(wih##g), "+v"(bias##g));

// Stage one 16B chunk of h from global (agent-scope, L2-bypass) into LDS.
#define STAGE_CHUNK(k, src, ldsrow) { \
  F2U lo_, hi_; \
  const float* p_ = (src) + 4*(ln + 64*(k)); \
  lo_.u = __hip_atomic_load((const unsigned long long*)p_, \
                            __ATOMIC_RELAXED, __HIP_MEMORY_SCOPE_AGENT); \
  hi_.u = __hip_atomic_load((const unsigned long long*)(p_ + 2), \
                            __ATOMIC_RELAXED, __HIP_MEMORY_SCOPE_AGENT); \
  vf4 t_; t_.x = lo_.f.x; t_.y = lo_.f.y; t_.z = hi_.f.x; t_.w = hi_.f.y; \
  *(vf4*)&(ldsrow)[4*(ln + 64*(k))] = t_; }

#define LDSREAD(k, ldsrow) \
  const vf4 hv##k = *(const vf4*)&(ldsrow)[4*(ln + 64*(k))];

#define FMA_G(g, c) \
  acc##g = __builtin_fmaf(w##g##_##c.x, h4_.x, acc##g); \
  acc##g = __builtin_fmaf(w##g##_##c.y, h4_.y, acc##g); \
  acc##g = __builtin_fmaf(w##g##_##c.z, h4_.z, acc##g); \
  acc##g = __builtin_fmaf(w##g##_##c.w, h4_.w, acc##g);

#define FMA_C(c) { const vf4 h4_ = hv##c; \
  FMA_G(0, c) FMA_G(1, c) FMA_G(2, c) FMA_G(3, c) }

#define REDUCE(g) { float a_ = acc##g; \
  a_ += __shfl_xor(a_, 1);  a_ += __shfl_xor(a_, 2);  a_ += __shfl_xor(a_, 4); \
  a_ += __shfl_xor(a_, 8);  a_ += __shfl_xor(a_, 16); a_ += __shfl_xor(a_, 32); \
  acc##g = a_ + bias##g; }

__global__ __launch_bounds__(NTHR, 2)
void lstm_persist(const float* __restrict__ x,
                  const float* __restrict__ W_ih,
                  const float* __restrict__ W_hh,
                  const float* __restrict__ b_ih,
                  const float* __restrict__ b_hh,
                  const float* __restrict__ W_lin,
                  const float* __restrict__ b_lin,
                  const float* __restrict__ W_out,
                  const float* __restrict__ b_out,
                  float* __restrict__ out,
                  float* __restrict__ ws)
{
  const int tid = threadIdx.x;
  const int b   = blockIdx.x;
  const int wv  = tid >> 6;
  const int ln  = tid & 63;

  float* hbuf0 = ws;            // [2048] ping  (even t)
  float* hbuf1 = ws + H;        // [2048] pong  (odd t)
  float* ylin  = ws + 2 * H;    // [2048]
  unsigned* leaves = (unsigned*)(ws + 4 * H);   // 8 counters, 64 uints apart
  unsigned* myleaf = leaves + (b & 7) * 64;

  __shared__ __align__(16) float h_lds[2][H];

  // ---- leaf reset: blocks 0..7 reset; EVERY block waits for ALL 8 leaves
  // to be un-poisoned before any arrive/poll (poison > any target!). ----
  if (tid == 0 && b < 8) {
    if (__hip_atomic_load(leaves + b * 64, __ATOMIC_RELAXED,
                          __HIP_MEMORY_SCOPE_AGENT) >= RESET_TH)
      __hip_atomic_store(leaves + b * 64, 0u, __ATOMIC_RELAXED,
                         __HIP_MEMORY_SCOPE_AGENT);
  }
  if (tid < 8) {
    while (__hip_atomic_load(leaves + tid * 64, __ATOMIC_RELAXED,
                             __HIP_MEMORY_SCOPE_AGENT) >= RESET_TH) {
      __builtin_amdgcn_s_sleep(1);
    }
  }

  // zero LDS row 0 (h_0 = 0, consumed at t=0 without staging)
  *(vf4*)&h_lds[0][4 * tid] = (vf4)(0.0f);

  // ---- persistent weights: load then PIN into registers ----
  const int j = b * 8 + wv;     // this wave's hidden unit
  DECLG(0) DECLG(1) DECLG(2) DECLG(3)
  LOADG(0) LOADG(1) LOADG(2) LOADG(3)
  PIN(0) PIN(1) PIN(2) PIN(3)

  __syncthreads();   // LDS zero + leaf reset visible block-wide

  float cst = 0.0f;   // cell state for unit j (all lanes redundant)

  #pragma unroll 1
  for (int t = 0; t < TSTEPS; ++t) {
    // x_t slice: regular cacheable load; latency overlaps the barrier wait
    const vf2 xr = *(const vf2*)(x + (long)t * FEAT + 2 * ln);
    float* ldsrow = h_lds[t & 1];

    if (t > 0 && wv == 0) {
      const unsigned target = 32u * (unsigned)t;
      if (ln < 8) {
        const unsigned* lp = leaves + ln * 64;
        while (__hip_atomic_load(lp, __ATOMIC_RELAXED,
                                 __HIP_MEMORY_SCOPE_AGENT) < target) {
          __builtin_amdgcn_s_sleep(1);
        }
      }
      // compiler ordering only; workgroup scope -> no buffer_inv
      __builtin_amdgcn_fence(__ATOMIC_ACQUIRE, "workgroup");
      const float* hsrc = (t & 1) ? hbuf1 : hbuf0;
      STAGE_CHUNK(0, hsrc, ldsrow) STAGE_CHUNK(1, hsrc, ldsrow)
      STAGE_CHUNK(2, hsrc, ldsrow) STAGE_CHUNK(3, hsrc, ldsrow)
      STAGE_CHUNK(4, hsrc, ldsrow) STAGE_CHUNK(5, hsrc, ldsrow)
      STAGE_CHUNK(6, hsrc, ldsrow) STAGE_CHUNK(7, hsrc, ldsrow)
    }
    __syncthreads();

    LDSREAD(0, ldsrow) LDSREAD(1, ldsrow) LDSREAD(2, ldsrow) LDSREAD(3, ldsrow)
    LDSREAD(4, ldsrow) LDSREAD(5, ldsrow) LDSREAD(6, ldsrow) LDSREAD(7, ldsrow)

    acc0 = wih0.x * xr.x + wih0.y * xr.y;
    acc1 = wih1.x * xr.x + wih1.y * xr.y;
    acc2 = wih2.x * xr.x + wih2.y * xr.y;
    acc3 = wih3.x * xr.x + wih3.y * xr.y;

    FMA_C(0) FMA_C(1) FMA_C(2) FMA_C(3)
    FMA_C(4) FMA_C(5) FMA_C(6) FMA_C(7)

    REDUCE(0) REDUCE(1) REDUCE(2) REDUCE(3)

    // gate order [i, f, g, o]
    const float iv = sigm(acc0);
    const float fv = sigm(acc1);
    const float gv = tanh_(acc2);
    const float ov = sigm(acc3);
    cst = fv * cst + iv * gv;
    const float hval = ov * tanh_(cst);

    if (ln == 0) {
      float* hdst = ((t + 1) & 1) ? hbuf1 : hbuf0;
      __hip_atomic_store(hdst + j, hval, __ATOMIC_RELAXED,
                         __HIP_MEMORY_SCOPE_AGENT);
    }
    // syncthreads implies per-wave s_waitcnt vmcnt(0) before s_barrier ->
    // every wave's h store is at L3 (sc1 bypass) before the leader arrives.
    __syncthreads();
    if (tid == 0) {
      __hip_atomic_fetch_add(myleaf, 1u, __ATOMIC_RELAXED,
                             __HIP_MEMORY_SCOPE_AGENT);
    }
  }

  // ---- head phase 1: ylin[j] = b_lin[j] + dot(W_lin[j,:], h_final) ----
  {
    float* ldsrow = h_lds[0];
    if (wv == 0) {
      const unsigned target = 32u * (unsigned)TSTEPS;
      if (ln < 8) {
        const unsigned* lp = leaves + ln * 64;
        while (__hip_atomic_load(lp, __ATOMIC_RELAXED,
                                 __HIP_MEMORY_SCOPE_AGENT) < target) {
          __builtin_amdgcn_s_sleep(1);
        }
      }
      __builtin_amdgcn_fence(__ATOMIC_ACQUIRE, "workgroup");
      const float* hsrc = hbuf0;    // h_8192: parity 0
      STAGE_CHUNK(0, hsrc, ldsrow) STAGE_CHUNK(1, hsrc, ldsrow)
      STAGE_CHUNK(2, hsrc, ldsrow) STAGE_CHUNK(3, hsrc, ldsrow)
      STAGE_CHUNK(4, hsrc, ldsrow) STAGE_CHUNK(5, hsrc, ldsrow)
      STAGE_CHUNK(6, hsrc, ldsrow) STAGE_CHUNK(7, hsrc, ldsrow)
    }
    __syncthreads();

    float a0 = 0.0f;
    const float* wl = W_lin + (long)j * H;
    #pragma unroll
    for (int k = 0; k < 8; ++k) {
      const vf4 h4 = *(const vf4*)&ldsrow[4 * (ln + 64 * k)];
      const vf4 u  = *(const vf4*)(wl + 4 * (ln + 64 * k));
      a0 += u.x * h4.x + u.y * h4.y + u.z * h4.z + u.w * h4.w;
    }
    a0 += __shfl_xor(a0, 1);  a0 += __shfl_xor(a0, 2);  a0 += __shfl_xor(a0, 4);
    a0 += __shfl_xor(a0, 8);  a0 += __shfl_xor(a0, 16); a0 += __shfl_xor(a0, 32);

    if (ln == 0) {
      __hip_atomic_store(ylin + j, a0 + b_lin[j], __ATOMIC_RELAXED,
                         __HIP_MEMORY_SCOPE_AGENT);
    }
    __syncthreads();
    if (tid == 0) {
      __hip_atomic_fetch_add(myleaf, 1u, __ATOMIC_RELAXED,
                             __HIP_MEMORY_SCOPE_AGENT);
    }
  }

  // ---- head phase 2: y = ylin @ W_out.T + b_out (block 0, wave 0) ----
  if (b == 0 && wv == 0) {
    const unsigned target = 32u * (unsigned)(TSTEPS + 1);
    if (ln < 8) {
      const unsigned* lp = leaves + ln * 64;
      while (__hip_atomic_load(lp, __ATOMIC_RELAXED,
                               __HIP_MEMORY_SCOPE_AGENT) < target) {
        __builtin_amdgcn_s_sleep(1);
      }
    }
    __builtin_amdgcn_fence(__ATOMIC_ACQUIRE, "workgroup");
    float p0 = 0.0f, p1 = 0.0f;
    #pragma unroll
    for (int k = 0; k < 8; ++k) {
      const int c = 4 * (ln + 64 * k);
      F2U ylo, yhi;
      ylo.u = __hip_atomic_load((const unsigned long long*)(ylin + c),
                                __ATOMIC_RELAXED, __HIP_MEMORY_SCOPE_AGENT);
      yhi.u = __hip_atomic_load((const unsigned long long*)(ylin + c + 2),
                                __ATOMIC_RELAXED, __HIP_MEMORY_SCOPE_AGENT);
      const float4 yv = make_float4(ylo.f.x, ylo.f.y, yhi.f.x, yhi.f.y);
      const vf4 q0 = *(const vf4*)(W_out + c);
      const vf4 q1 = *(const vf4*)(W_out + H + c);
      p0 += q0.x * yv.x + q0.y * yv.y + q0.z * yv.z + q0.w * yv.w;
      p1 += q1.x * yv.x + q1.y * yv.y + q1.z * yv.z + q1.w * yv.w;
    }
    p0 += __shfl_xor(p0, 1);  p0 += __shfl_xor(p0, 2);  p0 += __shfl_xor(p0, 4);
    p0 += __shfl_xor(p0, 8);  p0 += __shfl_xor(p0, 16); p0 += __shfl_xor(p0, 32);
    p1 += __shfl_xor(p1, 1);  p1 += __shfl_xor(p1, 2);  p1 += __shfl_xor(p1, 4);
    p1 += __shfl_xor(p1, 8);  p1 += __shfl_xor(p1, 16); p1 += __shfl_xor(p1, 32);
    if (ln == 0) {
      out[0] = p0 + b_out[0];
      out[1] = p1 + b_out[1];
    }
  }
}

extern "C" void kernel_launch(void* const* d_in, const int* in_sizes, int n_in,
                              void* d_out, int out_size, void* d_ws, size_t ws_size,
                              hipStream_t stream) {
  const float* x     = (const float*)d_in[0];
  const float* W_ih  = (const float*)d_in[1];
  const float* W_hh  = (const float*)d_in[2];
  const float* b_ih  = (const float*)d_in[3];
  const float* b_hh  = (const float*)d_in[4];
  const float* W_lin = (const float*)d_in[5];
  const float* b_lin = (const float*)d_in[6];
  const float* W_out = (const float*)d_in[7];
  const float* b_out = (const float*)d_in[8];

  lstm_persist<<<dim3(NBLK), dim3(NTHR), 0, stream>>>(
      x, W_ih, W_hh, b_ih, b_hh, W_lin, b_lin, W_out, b_out,
      (float*)d_out, (float*)d_ws);
}